// Round 4
// baseline (886.600 us; speedup 1.0000x reference)
//
#include <hip/hip_runtime.h>
#include <hip/hip_cooperative_groups.h>

namespace cg = cooperative_groups;

// topk cross-entropy: N=262144 rows, C=128 classes, K = int(0.7*N) = 183500.
// Round 4: cooperative mega-kernel with RUNTIME-SIZED grid (round 3 failed
// because GRID=1024 exceeded the runtime's cooperative capacity check).
// Deterministic host-query-based path choice + known-good multi-kernel
// fallback (round 2, absmax 0.0).

#define NCLASS 128
#define NREP 8
#define TPB 256
#define MAXGRID 2048

struct Scalars {
  unsigned sel1, sel2;
  unsigned cnt_above;   // cumulative count strictly above current prefix
  int krem;             // remaining rank within current prefix
  unsigned thr_bits;    // final: bit pattern of k-th largest
};

__device__ __forceinline__ unsigned suffix_incl_u(unsigned x, int lane) {
#pragma unroll
  for (int off = 1; off < 64; off <<= 1) {
    unsigned v = __shfl_down(x, off, 64);
    if (lane + off < 64) x += v;
  }
  return x;
}

// Descending-rank scan over NREP replicated histograms. Threads 0..63 only.
__device__ void scan_phase(const unsigned* __restrict__ hist, Scalars* sc,
                           int nbins, int phase, int K) {
  const int lane = threadIdx.x;       // 0..63
  const int bpt = nbins >> 6;         // bins per thread (64 or 16)
  const int Ktar = (phase == 0) ? K : sc->krem;

  unsigned csum = 0;
  for (int rr = 0; rr < NREP; ++rr) {
    const uint4* h4 = (const uint4*)(hist + (size_t)rr * nbins + lane * bpt);
    for (int i = 0; i < (bpt >> 2); ++i) {
      uint4 q = h4[i];
      csum += q.x + q.y + q.z + q.w;
    }
  }
  unsigned suf = suffix_incl_u(csum, lane);
  unsigned long long mask = __ballot(suf >= (unsigned)Ktar);
  int c = 63 - __builtin_clzll(mask);
  unsigned above_excl = suf - csum;
  unsigned aboveC = __shfl(above_excl, c, 64);   // strictly above chunk c

  unsigned h = 0;
  if (lane < bpt)
    for (int rr = 0; rr < NREP; ++rr) h += hist[(size_t)rr * nbins + c * bpt + lane];
  unsigned suf2 = suffix_incl_u(h, lane);
  unsigned long long mask2 = __ballot((lane < bpt) && (aboveC + suf2 >= (unsigned)Ktar));
  int u = 63 - __builtin_clzll(mask2);
  unsigned hU = __shfl(h, u, 64);
  unsigned suf2U = __shfl(suf2, u, 64);
  unsigned above = aboveC + suf2U - hU;          // strictly above selected bin
  int bin = c * bpt + u;

  if (lane == 0) {
    if (phase == 0) {
      sc->sel1 = (unsigned)bin; sc->cnt_above = above; sc->krem = Ktar - (int)above;
    } else if (phase == 1) {
      sc->sel2 = (unsigned)bin; sc->cnt_above += above; sc->krem = Ktar - (int)above;
    } else {
      sc->thr_bits = (sc->sel1 << 20) | (sc->sel2 << 10) | (unsigned)bin;
      sc->cnt_above += above;
    }
  }
}

// Shared loss+hist body (used by both mega and standalone kernels).
__device__ __forceinline__ void loss_hist_body(
    const float* __restrict__ x, const int* __restrict__ tgt,
    float* __restrict__ losses, unsigned* __restrict__ hist1,
    unsigned* lh, int N, int nblocks) {
  const int lane = threadIdx.x & 63;
  const int j = lane & 7;        // float4 column within row
  const int r = lane >> 3;       // row within the wave's 8-row group
  const int gw = blockIdx.x * (TPB / 64) + (threadIdx.x >> 6);
  const int W = nblocks * (TPB / 64);
  for (int base = gw; base * 8 < N; base += W) {
    const int row = base * 8 + r;
    const float4* rp = (const float4*)(x + (size_t)row * NCLASS);
    float4 a = rp[j];
    float4 b = rp[j + 8];
    float4 c = rp[j + 16];
    float4 d = rp[j + 24];
    int t = tgt[row];
    float xt = x[(size_t)row * NCLASS + t];   // L1 hit: row just streamed

    float m = fmaxf(fmaxf(fmaxf(a.x, a.y), fmaxf(a.z, a.w)),
                    fmaxf(fmaxf(b.x, b.y), fmaxf(b.z, b.w)));
    m = fmaxf(m, fmaxf(fmaxf(c.x, c.y), fmaxf(c.z, c.w)));
    m = fmaxf(m, fmaxf(fmaxf(d.x, d.y), fmaxf(d.z, d.w)));
    m = fmaxf(m, __shfl_xor(m, 1, 64));
    m = fmaxf(m, __shfl_xor(m, 2, 64));
    m = fmaxf(m, __shfl_xor(m, 4, 64));

    float s = __expf(a.x - m) + __expf(a.y - m) + __expf(a.z - m) + __expf(a.w - m)
            + __expf(b.x - m) + __expf(b.y - m) + __expf(b.z - m) + __expf(b.w - m)
            + __expf(c.x - m) + __expf(c.y - m) + __expf(c.z - m) + __expf(c.w - m)
            + __expf(d.x - m) + __expf(d.y - m) + __expf(d.z - m) + __expf(d.w - m);
    s += __shfl_xor(s, 1, 64);
    s += __shfl_xor(s, 2, 64);
    s += __shfl_xor(s, 4, 64);

    if (j == 0) {
      float loss = fmaxf(__logf(s) + m - xt, 0.0f);
      losses[row] = loss;
      atomicAdd(&lh[__float_as_uint(loss) >> 20], 1u);
    }
  }
  __syncthreads();
  unsigned* h = hist1 + (size_t)(blockIdx.x & (NREP - 1)) * 4096;
  for (int i = threadIdx.x; i < 4096; i += TPB) {
    unsigned v = lh[i];
    if (v) atomicAdd(&h[i], v);
  }
}

// ---------------- cooperative mega-kernel ----------------
__global__ __launch_bounds__(TPB, 2) void mega_kernel(
    const float* __restrict__ x, const int* __restrict__ tgt,
    float* __restrict__ losses, unsigned* __restrict__ hist1,
    unsigned* __restrict__ hist2, unsigned* __restrict__ hist3,
    Scalars* __restrict__ sc, double* __restrict__ partials,
    float* __restrict__ out, int N, int K) {
  cg::grid_group grid = cg::this_grid();
  __shared__ unsigned lh[4096];
  __shared__ double dsm[TPB / 64];

  const int lane = threadIdx.x & 63;
  const int G = gridDim.x;

  // ---- P0: zero LDS hist + global hist1 ----
  for (int i = threadIdx.x; i < 4096; i += TPB) lh[i] = 0;
  for (int i = blockIdx.x * TPB + threadIdx.x; i < NREP * 4096; i += G * TPB)
    hist1[i] = 0;
  __syncthreads();
  grid.sync();

  // ---- P1: losses + 12-bit histogram ----
  loss_hist_body(x, tgt, losses, hist1, lh, N, G);
  __threadfence();
  grid.sync();

  // ---- P2: scan level 1 (block 0); others zero hist2 ----
  if (blockIdx.x == 0) {
    if (threadIdx.x < 64) scan_phase(hist1, sc, 4096, 0, K);
  } else {
    for (int i = (blockIdx.x - 1) * TPB + threadIdx.x; i < NREP * 1024;
         i += (G - 1) * TPB)
      hist2[i] = 0;
  }
  __threadfence();
  grid.sync();

  const float4* L4 = (const float4*)losses;
  const int n4 = N >> 2;

  // ---- P3: refine 10 more bits (prefix = sel1) ----
  {
    for (int i = threadIdx.x; i < 1024; i += TPB) lh[i] = 0;
    __syncthreads();
    const unsigned prefix = sc->sel1;
    for (int idx = blockIdx.x * TPB + threadIdx.x; idx < n4; idx += G * TPB) {
      float4 v = L4[idx];
      unsigned b;
      b = __float_as_uint(v.x); if ((b >> 20) == prefix) atomicAdd(&lh[(b >> 10) & 1023u], 1u);
      b = __float_as_uint(v.y); if ((b >> 20) == prefix) atomicAdd(&lh[(b >> 10) & 1023u], 1u);
      b = __float_as_uint(v.z); if ((b >> 20) == prefix) atomicAdd(&lh[(b >> 10) & 1023u], 1u);
      b = __float_as_uint(v.w); if ((b >> 20) == prefix) atomicAdd(&lh[(b >> 10) & 1023u], 1u);
    }
    __syncthreads();
    unsigned* h = hist2 + (size_t)(blockIdx.x & (NREP - 1)) * 1024;
    for (int i = threadIdx.x; i < 1024; i += TPB) {
      unsigned v = lh[i];
      if (v) atomicAdd(&h[i], v);
    }
  }
  __threadfence();
  grid.sync();

  // ---- P4: scan level 2; others zero hist3 ----
  if (blockIdx.x == 0) {
    if (threadIdx.x < 64) scan_phase(hist2, sc, 1024, 1, K);
  } else {
    for (int i = (blockIdx.x - 1) * TPB + threadIdx.x; i < NREP * 1024;
         i += (G - 1) * TPB)
      hist3[i] = 0;
  }
  __threadfence();
  grid.sync();

  // ---- P5: refine final 10 bits ----
  {
    for (int i = threadIdx.x; i < 1024; i += TPB) lh[i] = 0;
    __syncthreads();
    const unsigned prefix = (sc->sel1 << 10) | sc->sel2;
    for (int idx = blockIdx.x * TPB + threadIdx.x; idx < n4; idx += G * TPB) {
      float4 v = L4[idx];
      unsigned b;
      b = __float_as_uint(v.x); if ((b >> 10) == prefix) atomicAdd(&lh[b & 1023u], 1u);
      b = __float_as_uint(v.y); if ((b >> 10) == prefix) atomicAdd(&lh[b & 1023u], 1u);
      b = __float_as_uint(v.z); if ((b >> 10) == prefix) atomicAdd(&lh[b & 1023u], 1u);
      b = __float_as_uint(v.w); if ((b >> 10) == prefix) atomicAdd(&lh[b & 1023u], 1u);
    }
    __syncthreads();
    unsigned* h = hist3 + (size_t)(blockIdx.x & (NREP - 1)) * 1024;
    for (int i = threadIdx.x; i < 1024; i += TPB) {
      unsigned v = lh[i];
      if (v) atomicAdd(&h[i], v);
    }
  }
  __threadfence();
  grid.sync();

  // ---- P6: scan level 3 -> threshold bits + count strictly greater ----
  if (blockIdx.x == 0 && threadIdx.x < 64) scan_phase(hist3, sc, 1024, 2, K);
  __threadfence();
  grid.sync();

  // ---- P7: sum of losses strictly greater than threshold ----
  {
    const unsigned thr = sc->thr_bits;
    double acc = 0.0;
    for (int idx = blockIdx.x * TPB + threadIdx.x; idx < n4; idx += G * TPB) {
      float4 v = L4[idx];
      if (__float_as_uint(v.x) > thr) acc += v.x;
      if (__float_as_uint(v.y) > thr) acc += v.y;
      if (__float_as_uint(v.z) > thr) acc += v.z;
      if (__float_as_uint(v.w) > thr) acc += v.w;
    }
#pragma unroll
    for (int off = 32; off > 0; off >>= 1) acc += __shfl_down(acc, off, 64);
    if (lane == 0) dsm[threadIdx.x >> 6] = acc;
    __syncthreads();
    if (threadIdx.x == 0)
      partials[blockIdx.x] = dsm[0] + dsm[1] + dsm[2] + dsm[3];
  }
  __threadfence();
  grid.sync();

  // ---- P8: final reduce + mean ----
  if (blockIdx.x == 0) {
    double s = 0.0;
    for (int i = threadIdx.x; i < G; i += TPB) s += partials[i];
#pragma unroll
    for (int off = 32; off > 0; off >>= 1) s += __shfl_down(s, off, 64);
    if (lane == 0) dsm[threadIdx.x >> 6] = s;
    __syncthreads();
    if (threadIdx.x == 0) {
      double thrv = (double)__uint_as_float(sc->thr_bits);
      double mean = (dsm[0] + dsm[1] + dsm[2] + dsm[3] +
                     (double)(K - (int)sc->cnt_above) * thrv) / (double)K;
      *out = (float)mean;
    }
  }
}

// ---------------- fallback multi-kernel path (round-2, known good) ----------------
__global__ __launch_bounds__(TPB) void loss_hist_kernel(
    const float* __restrict__ x, const int* __restrict__ tgt,
    float* __restrict__ losses, unsigned* __restrict__ hist1, int N, int nblocks) {
  __shared__ unsigned lh[4096];
  for (int i = threadIdx.x; i < 4096; i += TPB) lh[i] = 0;
  __syncthreads();
  loss_hist_body(x, tgt, losses, hist1, lh, N, nblocks);
}

__global__ void scan_kernel(const unsigned* __restrict__ hist, Scalars* sc,
                            int nbins, int phase, int K) {
  scan_phase(hist, sc, nbins, phase, K);
}

__global__ __launch_bounds__(TPB) void hist_refine_kernel(
    const float* __restrict__ losses, const Scalars* __restrict__ sc,
    unsigned* __restrict__ hist, int N, int phase) {
  __shared__ unsigned lh[1024];
  for (int i = threadIdx.x; i < 1024; i += TPB) lh[i] = 0;
  __syncthreads();
  unsigned prefix, shift;
  if (phase == 1) { prefix = sc->sel1; shift = 20; }
  else { prefix = (sc->sel1 << 10) | sc->sel2; shift = 10; }
  const unsigned sub_shift = shift - 10;
  const float4* L4 = (const float4*)losses;
  const int n4 = N >> 2;
  for (int idx = blockIdx.x * TPB + threadIdx.x; idx < n4; idx += gridDim.x * TPB) {
    float4 v = L4[idx];
    unsigned b;
    b = __float_as_uint(v.x); if ((b >> shift) == prefix) atomicAdd(&lh[(b >> sub_shift) & 1023u], 1u);
    b = __float_as_uint(v.y); if ((b >> shift) == prefix) atomicAdd(&lh[(b >> sub_shift) & 1023u], 1u);
    b = __float_as_uint(v.z); if ((b >> shift) == prefix) atomicAdd(&lh[(b >> sub_shift) & 1023u], 1u);
    b = __float_as_uint(v.w); if ((b >> shift) == prefix) atomicAdd(&lh[(b >> sub_shift) & 1023u], 1u);
  }
  __syncthreads();
  unsigned* h = hist + (size_t)(blockIdx.x & (NREP - 1)) * 1024;
  for (int i = threadIdx.x; i < 1024; i += TPB) {
    unsigned v = lh[i];
    if (v) atomicAdd(&h[i], v);
  }
}

__global__ __launch_bounds__(TPB) void sum_topk_kernel(
    const float* __restrict__ losses, const Scalars* __restrict__ sc,
    double* __restrict__ partials, int N) {
  const unsigned thr = sc->thr_bits;
  double acc = 0.0;
  const float4* L4 = (const float4*)losses;
  const int n4 = N >> 2;
  for (int idx = blockIdx.x * TPB + threadIdx.x; idx < n4; idx += gridDim.x * TPB) {
    float4 v = L4[idx];
    if (__float_as_uint(v.x) > thr) acc += v.x;
    if (__float_as_uint(v.y) > thr) acc += v.y;
    if (__float_as_uint(v.z) > thr) acc += v.z;
    if (__float_as_uint(v.w) > thr) acc += v.w;
  }
#pragma unroll
  for (int off = 32; off > 0; off >>= 1) acc += __shfl_down(acc, off, 64);
  __shared__ double wsum[4];
  if ((threadIdx.x & 63) == 0) wsum[threadIdx.x >> 6] = acc;
  __syncthreads();
  if (threadIdx.x == 0)
    partials[blockIdx.x] = wsum[0] + wsum[1] + wsum[2] + wsum[3];
}

__global__ void finalize_kernel(const double* __restrict__ partials,
                                const Scalars* __restrict__ sc,
                                float* __restrict__ out, int K, int npart) {
  const int lane = threadIdx.x;   // 64 threads
  double s = 0.0;
  for (int i = lane; i < npart; i += 64) s += partials[i];
#pragma unroll
  for (int off = 32; off > 0; off >>= 1) s += __shfl_down(s, off, 64);
  if (lane == 0) {
    double thr = (double)__uint_as_float(sc->thr_bits);
    double mean = (s + (double)(K - (int)sc->cnt_above) * thr) / (double)K;
    *out = (float)mean;
  }
}

extern "C" void kernel_launch(void* const* d_in, const int* in_sizes, int n_in,
                              void* d_out, int out_size, void* d_ws, size_t ws_size,
                              hipStream_t stream) {
  const float* x = (const float*)d_in[0];
  const int* tgt = (const int*)d_in[1];
  float* out = (float*)d_out;
  int N = in_sizes[1];                 // 262144 rows
  int K = (int)(0.7 * (double)N);      // 183500, matches Python int()

  char* ws = (char*)d_ws;
  const size_t OFF_H1 = (size_t)N * 4;                     // after losses (1 MiB)
  const size_t OFF_H2 = OFF_H1 + (size_t)NREP * 4096 * 4;  // +128 KiB
  const size_t OFF_H3 = OFF_H2 + (size_t)NREP * 1024 * 4;  // +32 KiB
  const size_t OFF_SC = OFF_H3 + (size_t)NREP * 1024 * 4;  // +32 KiB
  const size_t OFF_PT = OFF_SC + 256;                      // partials: 16 KiB

  float* losses = (float*)ws;
  unsigned* hist1 = (unsigned*)(ws + OFF_H1);
  unsigned* hist2 = (unsigned*)(ws + OFF_H2);
  unsigned* hist3 = (unsigned*)(ws + OFF_H3);
  Scalars* sc = (Scalars*)(ws + OFF_SC);
  double* partials = (double*)(ws + OFF_PT);

  // Deterministic, capture-safe host queries to size the cooperative grid.
  int dev = 0;
  (void)hipGetDevice(&dev);
  int coop = 0;
  (void)hipDeviceGetAttribute(&coop, hipDeviceAttributeCooperativeLaunch, dev);
  int nCU = 0;
  (void)hipDeviceGetAttribute(&nCU, hipDeviceAttributeMultiprocessorCount, dev);
  int blocksPerCU = 0;
  (void)hipOccupancyMaxActiveBlocksPerMultiprocessor(&blocksPerCU,
                                                     (const void*)mega_kernel,
                                                     TPB, 0);
  int grid = nCU * blocksPerCU;
  if (grid > MAXGRID) grid = MAXGRID;

  if (coop && grid >= 64) {
    void* args[] = {&x, &tgt, &losses, &hist1, &hist2, &hist3, &sc, &partials,
                    &out, &N, &K};
    hipError_t err = hipLaunchCooperativeKernel((const void*)mega_kernel,
                                                dim3(grid), dim3(TPB), args, 0,
                                                stream);
    if (err == hipSuccess) return;
    // Live-call failure: fall through to the multi-kernel path. (Path choice
    // is query-deterministic, so capture/live never diverge unless the launch
    // itself errors, in which case we also fell through on the live call.)
  }

  hipMemsetAsync(ws + OFF_H1, 0, OFF_PT - OFF_H1, stream);
  loss_hist_kernel<<<512, TPB, 0, stream>>>(x, tgt, losses, hist1, N, 512);
  scan_kernel<<<1, 64, 0, stream>>>(hist1, sc, 4096, 0, K);
  hist_refine_kernel<<<64, TPB, 0, stream>>>(losses, sc, hist2, N, 1);
  scan_kernel<<<1, 64, 0, stream>>>(hist2, sc, 1024, 1, K);
  hist_refine_kernel<<<64, TPB, 0, stream>>>(losses, sc, hist3, N, 2);
  scan_kernel<<<1, 64, 0, stream>>>(hist3, sc, 1024, 2, K);
  sum_topk_kernel<<<128, TPB, 0, stream>>>(losses, sc, partials, N);
  finalize_kernel<<<1, 64, 0, stream>>>(partials, sc, out, K, 128);
}

// Round 5
// 308.371 us; speedup vs baseline: 2.8751x; 2.8751x over previous
//
#include <hip/hip_runtime.h>

// topk cross-entropy: N=262144 rows, C=128 classes, K = int(0.7*N) = 183500.
// Round 5: multi-kernel (kernel-boundary sync is cheap on CDNA4; grid.sync is
// NOT — round 4 showed ~1.3 ms of fence/spin cost). 4 compute dispatches:
//   memset -> loss+hist12(+scan1 in last block)
//          -> refine20(+scan2+scan3 in last block)
//          -> sum(+finalize in last block)
// Exact 12/10/10-bit radix select on float bits (losses >= 0 => monotone);
// tie-exact mean = (sum_{v>thr} v + (K - cnt_gt)*thr) / K.

#define NCLASS 128
#define NREP 8
#define TPB 256
#define LOSS_GRID 512
#define SMALL_GRID 128

struct Scalars {
  unsigned sel1, sel2;
  unsigned cnt_above;   // count strictly above current prefix
  int krem;             // remaining rank within current prefix
  unsigned thr_bits;    // final: bit pattern of k-th largest
};

__device__ __forceinline__ unsigned aload_u(const unsigned* p) {
  return __hip_atomic_load(p, __ATOMIC_RELAXED, __HIP_MEMORY_SCOPE_AGENT);
}
__device__ __forceinline__ double aload_d(const double* p) {
  return __hip_atomic_load(p, __ATOMIC_RELAXED, __HIP_MEMORY_SCOPE_AGENT);
}

__device__ __forceinline__ unsigned suffix_incl_u(unsigned x, int lane) {
#pragma unroll
  for (int off = 1; off < 64; off <<= 1) {
    unsigned v = __shfl_down(x, off, 64);
    if (lane + off < 64) x += v;
  }
  return x;
}

// Last-block-done ticket. Every thread fences its own (atomic) writes before
// the block increments the ticket, so the last block can coherently read all
// atomically-written data via agent-scope loads.
__device__ __forceinline__ bool block_is_last(unsigned* ticket, unsigned nblocks) {
  __shared__ int amLast;
  __threadfence();
  __syncthreads();
  if (threadIdx.x == 0)
    amLast = (__hip_atomic_fetch_add(ticket, 1u, __ATOMIC_ACQ_REL,
                                     __HIP_MEMORY_SCOPE_AGENT) == nblocks - 1)
                 ? 1 : 0;
  __syncthreads();
  return amLast != 0;
}

// Descending-rank select on a histogram (nrep replicas summed), 64 lanes.
// Returns selected bin and count strictly above it (valid on all 64 lanes).
__device__ __forceinline__ void scan_desc(const unsigned* hist, int nbins,
                                          int nrep, unsigned Ktar,
                                          int* bin_out, unsigned* above_out) {
  const int lane = threadIdx.x;       // caller guarantees < 64
  const int bpt = nbins >> 6;
  unsigned csum = 0;
  for (int rr = 0; rr < nrep; ++rr) {
    const unsigned* hp = hist + (size_t)rr * nbins + lane * bpt;
    for (int i = 0; i < bpt; ++i) csum += aload_u(hp + i);
  }
  unsigned suf = suffix_incl_u(csum, lane);
  unsigned long long mask = __ballot(suf >= Ktar);
  int c = 63 - __builtin_clzll(mask);
  unsigned aboveC = __shfl(suf - csum, c, 64);   // strictly above chunk c

  unsigned h = 0;
  if (lane < bpt)
    for (int rr = 0; rr < nrep; ++rr)
      h += aload_u(hist + (size_t)rr * nbins + c * bpt + lane);
  unsigned suf2 = suffix_incl_u(h, lane);
  unsigned long long mask2 = __ballot((lane < bpt) && (aboveC + suf2 >= Ktar));
  int u = 63 - __builtin_clzll(mask2);
  unsigned above = aboveC + __shfl(suf2 - h, u, 64); // strictly above bin
  *bin_out = c * bpt + u;
  *above_out = above;
}

// ---- dispatch 2: losses + 12-bit histogram; last block does scan level 1 ----
__global__ __launch_bounds__(TPB) void loss_hist_kernel(
    const float* __restrict__ x, const int* __restrict__ tgt,
    float* __restrict__ losses, unsigned* __restrict__ hist1,
    Scalars* __restrict__ sc, unsigned* __restrict__ tickets, int N, int K) {
  __shared__ unsigned lh[4096];
  for (int i = threadIdx.x; i < 4096; i += TPB) lh[i] = 0;
  __syncthreads();

  const int lane = threadIdx.x & 63;
  const int j = lane & 7;        // float4 column within row
  const int r = lane >> 3;       // row within the wave's 8-row group
  const int gw = blockIdx.x * (TPB / 64) + (threadIdx.x >> 6);
  const int W = LOSS_GRID * (TPB / 64);
  for (int base = gw; base * 8 < N; base += W) {
    const int row = base * 8 + r;
    const float4* rp = (const float4*)(x + (size_t)row * NCLASS);
    float4 a = rp[j];
    float4 b = rp[j + 8];
    float4 c = rp[j + 16];
    float4 d = rp[j + 24];
    int t = tgt[row];
    float xt = x[(size_t)row * NCLASS + t];   // L1 hit: row just streamed

    float m = fmaxf(fmaxf(fmaxf(a.x, a.y), fmaxf(a.z, a.w)),
                    fmaxf(fmaxf(b.x, b.y), fmaxf(b.z, b.w)));
    m = fmaxf(m, fmaxf(fmaxf(c.x, c.y), fmaxf(c.z, c.w)));
    m = fmaxf(m, fmaxf(fmaxf(d.x, d.y), fmaxf(d.z, d.w)));
    m = fmaxf(m, __shfl_xor(m, 1, 64));
    m = fmaxf(m, __shfl_xor(m, 2, 64));
    m = fmaxf(m, __shfl_xor(m, 4, 64));

    float s = __expf(a.x - m) + __expf(a.y - m) + __expf(a.z - m) + __expf(a.w - m)
            + __expf(b.x - m) + __expf(b.y - m) + __expf(b.z - m) + __expf(b.w - m)
            + __expf(c.x - m) + __expf(c.y - m) + __expf(c.z - m) + __expf(c.w - m)
            + __expf(d.x - m) + __expf(d.y - m) + __expf(d.z - m) + __expf(d.w - m);
    s += __shfl_xor(s, 1, 64);
    s += __shfl_xor(s, 2, 64);
    s += __shfl_xor(s, 4, 64);

    if (j == 0) {
      float loss = fmaxf(__logf(s) + m - xt, 0.0f);
      losses[row] = loss;
      atomicAdd(&lh[__float_as_uint(loss) >> 20], 1u);
    }
  }
  __syncthreads();
  unsigned* h = hist1 + (size_t)(blockIdx.x & (NREP - 1)) * 4096;
  for (int i = threadIdx.x; i < 4096; i += TPB) {
    unsigned v = lh[i];
    if (v) atomicAdd(&h[i], v);
  }

  if (block_is_last(&tickets[0], LOSS_GRID) && threadIdx.x < 64) {
    int bin; unsigned above;
    scan_desc(hist1, 4096, NREP, (unsigned)K, &bin, &above);
    if (threadIdx.x == 0) {
      sc->sel1 = (unsigned)bin;
      sc->cnt_above = above;
      sc->krem = K - (int)above;
    }
  }
}

// ---- dispatch 3: 20-bit refine (coarse LDS 1024 + sparse global 1M fine);
//      last block does scan levels 2 and 3 ----
__global__ __launch_bounds__(TPB) void refine_kernel(
    const float* __restrict__ losses, unsigned* __restrict__ hist2,
    unsigned* __restrict__ fine, Scalars* __restrict__ sc,
    unsigned* __restrict__ tickets, int N) {
  __shared__ unsigned lh[1024];
  for (int i = threadIdx.x; i < 1024; i += TPB) lh[i] = 0;
  __syncthreads();

  const unsigned prefix = sc->sel1;
  const float4* L4 = (const float4*)losses;
  const int n4 = N >> 2;
  for (int idx = blockIdx.x * TPB + threadIdx.x; idx < n4;
       idx += SMALL_GRID * TPB) {
    float4 v = L4[idx];
    unsigned b;
    b = __float_as_uint(v.x);
    if ((b >> 20) == prefix) { atomicAdd(&lh[(b >> 10) & 1023u], 1u); atomicAdd(&fine[b & 0xFFFFFu], 1u); }
    b = __float_as_uint(v.y);
    if ((b >> 20) == prefix) { atomicAdd(&lh[(b >> 10) & 1023u], 1u); atomicAdd(&fine[b & 0xFFFFFu], 1u); }
    b = __float_as_uint(v.z);
    if ((b >> 20) == prefix) { atomicAdd(&lh[(b >> 10) & 1023u], 1u); atomicAdd(&fine[b & 0xFFFFFu], 1u); }
    b = __float_as_uint(v.w);
    if ((b >> 20) == prefix) { atomicAdd(&lh[(b >> 10) & 1023u], 1u); atomicAdd(&fine[b & 0xFFFFFu], 1u); }
  }
  __syncthreads();
  unsigned* h = hist2 + (size_t)(blockIdx.x & (NREP - 1)) * 1024;
  for (int i = threadIdx.x; i < 1024; i += TPB) {
    unsigned v = lh[i];
    if (v) atomicAdd(&h[i], v);
  }

  if (block_is_last(&tickets[1], SMALL_GRID) && threadIdx.x < 64) {
    int bin; unsigned above;
    scan_desc(hist2, 1024, NREP, (unsigned)sc->krem, &bin, &above);
    unsigned sel2 = (unsigned)bin;
    unsigned krem2 = (unsigned)sc->krem - above;
    unsigned cnt2 = sc->cnt_above + above;
    int bin3; unsigned above3;
    scan_desc(fine + (size_t)sel2 * 1024, 1024, 1, krem2, &bin3, &above3);
    if (threadIdx.x == 0) {
      sc->thr_bits = (sc->sel1 << 20) | (sel2 << 10) | (unsigned)bin3;
      sc->cnt_above = cnt2 + above3;
    }
  }
}

// ---- dispatch 4: sum of losses strictly > thr; last block finalizes ----
__global__ __launch_bounds__(TPB) void sum_topk_kernel(
    const float* __restrict__ losses, const Scalars* __restrict__ sc,
    double* __restrict__ partials, unsigned* __restrict__ tickets,
    float* __restrict__ out, int N, int K) {
  const unsigned thr = sc->thr_bits;
  double acc = 0.0;
  const float4* L4 = (const float4*)losses;
  const int n4 = N >> 2;
  for (int idx = blockIdx.x * TPB + threadIdx.x; idx < n4;
       idx += SMALL_GRID * TPB) {
    float4 v = L4[idx];
    if (__float_as_uint(v.x) > thr) acc += v.x;
    if (__float_as_uint(v.y) > thr) acc += v.y;
    if (__float_as_uint(v.z) > thr) acc += v.z;
    if (__float_as_uint(v.w) > thr) acc += v.w;
  }
#pragma unroll
  for (int off = 32; off > 0; off >>= 1) acc += __shfl_down(acc, off, 64);
  __shared__ double dsm[TPB / 64];
  if ((threadIdx.x & 63) == 0) dsm[threadIdx.x >> 6] = acc;
  __syncthreads();
  if (threadIdx.x == 0)
    partials[blockIdx.x] = dsm[0] + dsm[1] + dsm[2] + dsm[3];

  if (block_is_last(&tickets[2], SMALL_GRID)) {
    double s = 0.0;
    for (int i = threadIdx.x; i < SMALL_GRID; i += TPB) s += aload_d(&partials[i]);
#pragma unroll
    for (int off = 32; off > 0; off >>= 1) s += __shfl_down(s, off, 64);
    if ((threadIdx.x & 63) == 0) dsm[threadIdx.x >> 6] = s;
    __syncthreads();
    if (threadIdx.x == 0) {
      double thrv = (double)__uint_as_float(sc->thr_bits);
      double mean = (dsm[0] + dsm[1] + dsm[2] + dsm[3] +
                     (double)(K - (int)sc->cnt_above) * thrv) / (double)K;
      *out = (float)mean;
    }
  }
}

extern "C" void kernel_launch(void* const* d_in, const int* in_sizes, int n_in,
                              void* d_out, int out_size, void* d_ws, size_t ws_size,
                              hipStream_t stream) {
  const float* x = (const float*)d_in[0];
  const int* tgt = (const int*)d_in[1];
  float* out = (float*)d_out;
  int N = in_sizes[1];                 // 262144 rows
  int K = (int)(0.7 * (double)N);      // 183500, matches Python int()

  char* ws = (char*)d_ws;
  const size_t OFF_H1 = (size_t)N * 4;                       // losses: 1 MiB
  const size_t OFF_H2 = OFF_H1 + (size_t)NREP * 4096 * 4;    // hist1: 128 KiB
  const size_t OFF_FN = OFF_H2 + (size_t)NREP * 1024 * 4;    // hist2: 32 KiB
  const size_t OFF_SC = OFF_FN + (size_t)(1u << 20) * 4;     // fine: 4 MiB
  const size_t OFF_TK = OFF_SC + 64;                         // scalars
  const size_t OFF_PT = OFF_TK + 64;                         // tickets
  // partials: SMALL_GRID doubles after OFF_PT (written before read; no zeroing)

  float* losses = (float*)ws;
  unsigned* hist1 = (unsigned*)(ws + OFF_H1);
  unsigned* hist2 = (unsigned*)(ws + OFF_H2);
  unsigned* fine = (unsigned*)(ws + OFF_FN);
  Scalars* sc = (Scalars*)(ws + OFF_SC);
  unsigned* tickets = (unsigned*)(ws + OFF_TK);
  double* partials = (double*)(ws + OFF_PT);

  // zero hist1 + hist2 + fine + scalars + tickets in one fill
  hipMemsetAsync(ws + OFF_H1, 0, OFF_PT - OFF_H1, stream);

  loss_hist_kernel<<<LOSS_GRID, TPB, 0, stream>>>(x, tgt, losses, hist1, sc,
                                                  tickets, N, K);
  refine_kernel<<<SMALL_GRID, TPB, 0, stream>>>(losses, hist2, fine, sc,
                                                tickets, N);
  sum_topk_kernel<<<SMALL_GRID, TPB, 0, stream>>>(losses, sc, partials,
                                                  tickets, out, N, K);
}